// Round 15
// baseline (268.345 us; speedup 1.0000x reference)
//
#include <hip/hip_runtime.h>

// ---------------------------------------------------------------------------
// YOLOv3 post-processing pipeline (round 21):
//   Base = round-18 (239.2us best). ONE change: k_topk at 384 threads with
//   __launch_bounds__(384, 4).
//   r19 post-mortem separated two effects: the one-round grid shape WORKED
//   (occupancy 43->60%) but its (384,8) bound capped VGPR at 64 -> 6-group
//   keygen spilled (WRITE 76MB, 5th cap-spill). (384,4) keeps the proven
//   128-VGPR cap; at ~48 actual VGPR the HW still resides 8 waves/SIMD ->
//   5 six-wave blocks/CU -> 1280 = 256x5 blocks in ONE round, no ragged tail.
//   K1 k_conf  : conf-only producer (r18, verbatim; r20's fusion was neutral)
//   K3 k_final : 1024 threads (r18, verbatim)
// ---------------------------------------------------------------------------

#define NTOT   22743      // 3*(19^2 + 38^2 + 76^2)
#define NCLS   80
#define TOPK   100
#define KPAD   22752      // row stride for conf_q (16B aligned, 8-div)
#define NG2    2166       // 8-key groups in layer 2 (17328 keys)
#define Q_L1   17328
#define Q_L0   21660
#define NT     384        // 6 waves/block, 5 blocks/CU, single round
#define SCORE_THR 0.2f
#define NMS_THR   0.3f

__device__ __forceinline__ float sig_exact(float x) {
    return 1.0f / (1.0f + expf(-x));          // precise OCML expf + IEEE div
}
__device__ __forceinline__ float sig_fast(float x) {
    // monotone surrogate, rel err ~1e-6 << 2^-7 bin margin
    return __builtin_amdgcn_rcpf(1.0f + __expf(-x));
}
__device__ __forceinline__ unsigned pack2(float cfa, float lga, float cfb, float lgb) {
    unsigned ka = __float_as_uint(cfa * sig_fast(lga)) >> 16;
    unsigned kb = __float_as_uint(cfb * sig_fast(lgb)) >> 16;
    return ka | (kb << 16);
}

// -------------------------- K1: conf-only producer ------------------------
__global__ __launch_bounds__(256) void k_conf(
    const float* __restrict__ f0, const float* __restrict__ f1,
    const float* __restrict__ f2, float* __restrict__ conf_q, int total) {
    int gid = blockIdx.x * 256 + threadIdx.x;
    if (gid >= total) return;
    int b = gid / NTOT; int q = gid - b * NTOT;
    const float* f; int ghw, a, s;
    if (q < Q_L1)      { f = f2; ghw = 5776; a = q / 5776;  s = q - a * 5776; }
    else if (q < Q_L0) { f = f1; ghw = 1444; int r = q - Q_L1; a = r / 1444; s = r - a * 1444; }
    else               { f = f0; ghw = 361;  int r = q - Q_L0; a = r / 361;  s = r - a * 361; }
    // consecutive q -> consecutive s within a plane: coalesced load & store
    float tc = f[((size_t)(b * 255 + a * 85 + 4)) * ghw + s];
    conf_q[(size_t)b * KPAD + q] = sig_exact(tc);
}

// ------------------ shared select helpers ---------------------------------
__device__ void find_pivot(unsigned* hist, int H, unsigned target,
                           unsigned* suf, unsigned* sh_p, unsigned* sh_above) {
    const int tid = threadIdx.x;
    const int per = H >> 8;
    if (tid < 256) {
        unsigned acc = 0;
        for (int u = 0; u < per; ++u) acc += hist[tid * per + u];
        suf[tid] = acc;
    }
    __syncthreads();
    for (int off = 1; off < 256; off <<= 1) {
        unsigned v = 0;
        if (tid < 256) v = (tid + off < 256) ? suf[tid + off] : 0u;
        __syncthreads();
        if (tid < 256) suf[tid] += v;
        __syncthreads();
    }
    if (tid < 256) {
        unsigned mysuf = suf[tid];
        unsigned nxt = (tid == 255) ? 0u : suf[tid + 1];
        if (mysuf >= target && nxt < target) {
            unsigned above = nxt;
            for (int h = tid * per + per - 1; h >= tid * per; --h) {
                unsigned c2 = above + hist[h];
                if (c2 >= target) { *sh_p = (unsigned)h; *sh_above = above; break; }
                above = c2;
            }
        }
    }
    __syncthreads();
}

// -------------------------- K2: fused topk + NMS --------------------------
__device__ __forceinline__ void collect_cand(
    int b, int c, int q, const float* __restrict__ f0,
    const float* __restrict__ f1, const float* __restrict__ f2,
    const float* __restrict__ conf_q, unsigned long long* buf,
    unsigned* sh_cnt) {
    int a, s, nbase, ghw;
    const float* f;
    if (q < Q_L1)      { a = q / 5776;  s = q - a * 5776;  f = f2; ghw = 5776; nbase = 5415; }
    else if (q < Q_L0) { int r = q - Q_L1; a = r / 1444; s = r - a * 1444; f = f1; ghw = 1444; nbase = 1083; }
    else               { int r = q - Q_L0; a = r / 361;  s = r - a * 361;  f = f0; ghw = 361;  nbase = 0;    }
    float t  = f[((size_t)(b * 255 + a * 85 + 5 + c)) * ghw + s];
    float cf = conf_q[(size_t)b * KPAD + q];
    float sce = cf * sig_exact(t);
    int n = nbase + 3 * s + a;
    unsigned slot = atomicAdd(sh_cnt, 1u);
    if (slot < 512)
        buf[slot] = (((unsigned long long)__float_as_uint(sce)) << 32)
                    | (unsigned)(~n);
}

__device__ __forceinline__ void hist8(unsigned* histp, unsigned w0, unsigned w1,
                                      unsigned w2, unsigned w3) {
    unsigned ks[8] = { w0 & 0xFFFFu, w0 >> 16, w1 & 0xFFFFu, w1 >> 16,
                       w2 & 0xFFFFu, w2 >> 16, w3 & 0xFFFFu, w3 >> 16 };
    #pragma unroll
    for (int j = 0; j < 8; ++j)
        atomicAdd(&histp[ks[j] >> 2], 1u << (((ks[j] >> 1) & 1u) * 16));
}

__global__ __launch_bounds__(NT, 4) void k_topk(
    const float* __restrict__ f0, const float* __restrict__ f1,
    const float* __restrict__ f2, const float* __restrict__ conf_q,
    const float* __restrict__ anchors, const float* __restrict__ imshape,
    float4* __restrict__ top_b, float* __restrict__ cand) {
    __shared__ unsigned int histp[4096];           // packed u16x2: 8192 bins, 16 KB
    __shared__ unsigned long long buf[512];        // 4 KB
    __shared__ unsigned int wsum[4];
    __shared__ float sb_y1[TOPK], sb_x1[TOPK], sb_y2[TOPK], sb_x2[TOPK], sb_s[TOPK];
    __shared__ unsigned int sh_p, sh_cnt;

    const int tid = threadIdx.x;
    const int row = blockIdx.x;
    const int b = row / NCLS, c = row - b * NCLS;
    const float* cq = conf_q + (size_t)b * KPAD;

    for (int i = tid; i < 4096; i += NT) histp[i] = 0;
    if (tid == 0) sh_cnt = 0;
    __syncthreads();                               // hist zeroed BEFORE keygen

    // ---- keygen + histogram FUSED (r15 form); layer 2: 6 groups/thread ---
    uint4 v[6];
    bool  val[6];
    #pragma unroll
    for (int k = 0; k < 6; ++k) {
        int g = tid + k * NT;
        val[k] = (g < NG2);
        if (val[k]) {
            int q = g * 8;
            int a = q / 5776, s = q - a * 5776;
            const float* fp = f2 + ((size_t)(b * 255 + a * 85 + 5 + c)) * 5776 + s;
            float4 l0 = *(const float4*)fp;
            float4 l1 = *(const float4*)(fp + 4);
            float4 c0 = *(const float4*)(cq + q);
            float4 c1 = *(const float4*)(cq + q + 4);
            v[k].x = pack2(c0.x, l0.x, c0.y, l0.y);
            v[k].y = pack2(c0.z, l0.z, c0.w, l0.w);
            v[k].z = pack2(c1.x, l1.x, c1.y, l1.y);
            v[k].w = pack2(c1.z, l1.z, c1.w, l1.w);
            hist8(histp, v[k].x, v[k].y, v[k].z, v[k].w);
        } else v[k] = make_uint4(0, 0, 0, 0);
    }

    // layer 1: 3 whole planes, one float4/thread (tid<361), fused atomics
    const bool lv = (tid < 361);
    unsigned k1p[6];
    if (lv) {
        #pragma unroll
        for (int p = 0; p < 3; ++p) {
            const float* fp = f1 + ((size_t)(b * 255 + p * 85 + 5 + c)) * 1444 + 4 * tid;
            float4 lg = *(const float4*)fp;
            float4 cf = *(const float4*)(cq + Q_L1 + p * 1444 + 4 * tid);
            unsigned w0 = pack2(cf.x, lg.x, cf.y, lg.y);
            unsigned w1 = pack2(cf.z, lg.z, cf.w, lg.w);
            k1p[2*p] = w0; k1p[2*p+1] = w1;
            unsigned ks[4] = { w0 & 0xFFFFu, w0 >> 16, w1 & 0xFFFFu, w1 >> 16 };
            #pragma unroll
            for (int j = 0; j < 4; ++j)
                atomicAdd(&histp[ks[j] >> 2], 1u << (((ks[j] >> 1) & 1u) * 16));
        }
    }

    // layer 0: 3 planes, one scalar/thread (tid<361), fused atomics
    unsigned k0[3];
    if (lv) {
        #pragma unroll
        for (int p = 0; p < 3; ++p) {
            float g0 = f0[((size_t)(b * 255 + p * 85 + 5 + c)) * 361 + tid];
            float c0 = cq[Q_L0 + p * 361 + tid];
            k0[p] = __float_as_uint(c0 * sig_fast(g0)) >> 16;
            atomicAdd(&histp[k0[p] >> 2], 1u << (((k0[p] >> 1) & 1u) * 16));
        }
    }
    __syncthreads();

    // pivot: group t (tid<256) covers bins [t*32,t*32+32) = words [t*16,t*16+16)
    {
        const int lane = tid & 63;
        unsigned own = 0;
        if (tid < 256) {
            #pragma unroll
            for (int u = 0; u < 16; ++u) {
                unsigned w = histp[tid * 16 + u];
                own += (w & 0xFFFFu) + (w >> 16);
            }
        }
        unsigned acc = own;                        // wave-level suffix scan
        #pragma unroll
        for (int d = 1; d < 64; d <<= 1) {
            unsigned vv = __shfl_down(acc, d, 64);
            if (lane + d < 64) acc += vv;
        }
        if (tid < 256 && lane == 0) wsum[tid >> 6] = acc;
        __syncthreads();
        if (tid < 256) {
            unsigned tail = 0;
            for (int w2 = (tid >> 6) + 1; w2 < 4; ++w2) tail += wsum[w2];
            unsigned suft = acc + tail;            // suffix incl own group
            unsigned nxt  = suft - own;            // suffix of groups above
            if (suft >= TOPK && nxt < TOPK) {
                unsigned above = nxt;
                for (int bb = 31; bb >= 0; --bb) {
                    unsigned w = histp[tid * 16 + (bb >> 1)];
                    unsigned cnt = (bb & 1) ? (w >> 16) : (w & 0xFFFFu);
                    if (above + cnt >= TOPK) { sh_p = (unsigned)(tid * 32 + bb); break; }
                    above += cnt;
                }
            }
        }
        __syncthreads();
    }
    const unsigned kthr = sh_p > 0 ? ((sh_p - 1) << 1) : 0u;  // one-bin margin

    // pass 2: collect candidates FROM REGISTERS, exact rescore
    #pragma unroll
    for (int k = 0; k < 6; ++k) if (val[k]) {
        unsigned ks[8] = { v[k].x & 0xFFFFu, v[k].x >> 16, v[k].y & 0xFFFFu, v[k].y >> 16,
                           v[k].z & 0xFFFFu, v[k].z >> 16, v[k].w & 0xFFFFu, v[k].w >> 16 };
        #pragma unroll
        for (int j = 0; j < 8; ++j)
            if (ks[j] >= kthr)
                collect_cand(b, c, (tid + k * NT) * 8 + j, f0, f1, f2, conf_q, buf, &sh_cnt);
    }
    if (lv) {
        #pragma unroll
        for (int p = 0; p < 3; ++p) {
            unsigned ks[4] = { k1p[2*p] & 0xFFFFu, k1p[2*p] >> 16,
                               k1p[2*p+1] & 0xFFFFu, k1p[2*p+1] >> 16 };
            #pragma unroll
            for (int j = 0; j < 4; ++j)
                if (ks[j] >= kthr)
                    collect_cand(b, c, Q_L1 + p * 1444 + 4 * tid + j, f0, f1, f2, conf_q, buf, &sh_cnt);
            if (k0[p] >= kthr)
                collect_cand(b, c, Q_L0 + p * 361 + tid, f0, f1, f2, conf_q, buf, &sh_cnt);
        }
    }
    __syncthreads();

    // rank-by-count (strided); box decoded INLINE for rank<TOPK (r18 form)
    const int M = (int)min(sh_cnt, 512u);
    for (int i = tid; i < M; i += NT) {
        unsigned long long mykey = buf[i];
        int rank = 0;
        for (int j = 0; j < M; ++j) rank += (buf[j] > mykey);   // LDS broadcast
        if (rank < TOPK) {
            int nn = (int)(~(unsigned)mykey);
            const float* f; int ghw, gw, l, off;
            if (nn < 1083)      { f = f0; off = 0;    ghw = 361;  gw = 19; l = 0; }
            else if (nn < 5415) { f = f1; off = 1083; ghw = 1444; gw = 38; l = 1; }
            else                { f = f2; off = 5415; ghw = 5776; gw = 76; l = 2; }
            int m2 = nn - off; int a = m2 % 3; int s = m2 / 3;
            int y = s / gw, x = s - y * gw;
            const float* qp = f + ((size_t)(b * 255 + a * 85)) * ghw + s;
            float tx = qp[0], ty = qp[(size_t)ghw];
            float tw = qp[2 * (size_t)ghw], th = qp[3 * (size_t)ghw];
            int arow = (2 - l) * 3 + a;
            float aw = anchors[arow * 2], ah = anchors[arow * 2 + 1];
            float imh = imshape[0], imw = imshape[1];
            float gf = (float)gw;
            float bxx = (sig_exact(tx) + (float)x) / gf;
            float bxy = (sig_exact(ty) + (float)y) / gf;
            float bw  = expf(tw) * aw / 608.0f;
            float bh  = expf(th) * ah / 608.0f;
            float r  = fminf(608.0f / imh, 608.0f / imw);
            float nh = rintf(imh * r), nw2 = rintf(imw * r);
            float offy = (608.0f - nh) / 2.0f / 608.0f;
            float offx = (608.0f - nw2) / 2.0f / 608.0f;
            float scy = 608.0f / nh, scx = 608.0f / nw2;
            float cy = (bxy - offy) * scy;
            float cx = (bxx - offx) * scx;
            float hh = bh * scy, ww = bw * scx;
            float4 bx = make_float4((cy - hh / 2.0f) * imh, (cx - ww / 2.0f) * imw,
                                    (cy + hh / 2.0f) * imh, (cx + ww / 2.0f) * imw);
            sb_y1[rank] = bx.x; sb_x1[rank] = bx.y;
            sb_y2[rank] = bx.z; sb_x2[rank] = bx.w;
            sb_s[rank]  = __uint_as_float((unsigned)(mykey >> 32));
            top_b[(size_t)row * TOPK + rank] = bx;
        }
    }
    __syncthreads();

    // fused greedy NMS on wave 0 (reference-exact op order)
    if (tid < 64) {
        const int j0 = tid, j1 = tid + 64;
        const bool v1 = (j1 < TOPK);
        float y10 = sb_y1[j0], x10 = sb_x1[j0], y20 = sb_y2[j0], x20 = sb_x2[j0];
        float s0 = sb_s[j0];
        float y11 = v1 ? sb_y1[j1] : 0.f, x11 = v1 ? sb_x1[j1] : 0.f;
        float y21 = v1 ? sb_y2[j1] : 0.f, x21 = v1 ? sb_x2[j1] : 0.f;
        float s1 = v1 ? sb_s[j1] : -1.0f;
        float ar0 = fmaxf(y20 - y10, 0.f) * fmaxf(x20 - x10, 0.f);
        float ar1 = fmaxf(y21 - y11, 0.f) * fmaxf(x21 - x11, 0.f);
        int sup0 = 0, sup1 = 0;
        for (int i = 0; i < TOPK; ++i) {
            float yi1 = sb_y1[i], xi1 = sb_x1[i], yi2 = sb_y2[i], xi2 = sb_x2[i];
            float si = sb_s[i];
            int supi = (i < 64) ? __shfl(sup0, i, 64) : __shfl(sup1, i - 64, 64);
            bool keep_i = (si >= SCORE_THR) && (supi == 0);
            if (keep_i) {
                float ari = fmaxf(yi2 - yi1, 0.f) * fmaxf(xi2 - xi1, 0.f);
                if (j0 > i) {
                    float ty1 = fmaxf(yi1, y10), tx1 = fmaxf(xi1, x10);
                    float ty2 = fminf(yi2, y20), tx2 = fminf(xi2, x20);
                    float inter = fmaxf(ty2 - ty1, 0.f) * fmaxf(tx2 - tx1, 0.f);
                    float iou = inter / (ari + ar0 - inter + 1e-9f);
                    if (iou > NMS_THR) sup0 = 1;
                }
                if (v1 && j1 > i) {
                    float ty1 = fmaxf(yi1, y11), tx1 = fmaxf(xi1, x11);
                    float ty2 = fminf(yi2, y21), tx2 = fminf(xi2, x21);
                    float inter = fmaxf(ty2 - ty1, 0.f) * fmaxf(tx2 - tx1, 0.f);
                    float iou = inter / (ari + ar1 - inter + 1e-9f);
                    if (iou > NMS_THR) sup1 = 1;
                }
            }
        }
        cand[(size_t)row * TOPK + j0] = (s0 >= SCORE_THR && sup0 == 0) ? s0 : -1.0f;
        if (v1)
            cand[(size_t)row * TOPK + j1] = (s1 >= SCORE_THR && sup1 == 0) ? s1 : -1.0f;
    }
}

// -------------------------- K3: per-image top-100 -------------------------
#define FBS 1024
__global__ __launch_bounds__(FBS) void k_final(
    const float* __restrict__ cand, const float4* __restrict__ top_b,
    float* __restrict__ out) {
    __shared__ float cs[8000];                     // 32 KB
    __shared__ unsigned int hist[4096];            // 16 KB
    __shared__ unsigned long long buf[512];
    __shared__ unsigned int suf[256];
    __shared__ unsigned int sh_kp, sh_p1, sh_above1, sh_p2, sh_above2, sh_cnt;

    const int tid = threadIdx.x, b = blockIdx.x;
    if (tid == 0) { sh_kp = 0; sh_cnt = 0; }
    for (int i = tid; i < 4096; i += FBS) hist[i] = 0;
    __syncthreads();

    unsigned lk = 0;
    for (int i = tid; i < 8000; i += FBS) {
        float v = cand[b * 8000 + i];
        cs[i] = v;
        if (v > -0.5f) lk++;
    }
    atomicAdd(&sh_kp, lk);
    __syncthreads();
    unsigned Kp = sh_kp;

    if (Kp >= TOPK) {
        for (int i = tid; i < 8000; i += FBS)
            if (cs[i] > -0.5f) atomicAdd(&hist[__float_as_uint(cs[i]) >> 19], 1u);
        __syncthreads();
        find_pivot(hist, 2048, TOPK, suf, &sh_p1, &sh_above1);
        unsigned p1 = sh_p1, above1 = sh_above1;
        for (int i = tid; i < 4096; i += FBS) hist[i] = 0;
        __syncthreads();
        for (int i = tid; i < 8000; i += FBS) {
            float v = cs[i];
            if (v > -0.5f) {
                unsigned bits = __float_as_uint(v);
                if ((bits >> 19) == p1) atomicAdd(&hist[(bits >> 7) & 0xFFFu], 1u);
            }
        }
        __syncthreads();
        find_pivot(hist, 4096, TOPK - above1, suf, &sh_p2, &sh_above2);
        unsigned p2 = sh_p2;
        for (int i = tid; i < 8000; i += FBS) {
            float v = cs[i];
            if (v > -0.5f) {
                unsigned bits = __float_as_uint(v);
                unsigned b1 = bits >> 19;
                if (b1 > p1 || (b1 == p1 && ((bits >> 7) & 0xFFFu) >= p2)) {
                    unsigned slot = atomicAdd(&sh_cnt, 1u);
                    if (slot < 512)
                        buf[slot] = (((unsigned long long)bits) << 32) | (unsigned)(~i);
                }
            }
        }
    } else {
        // < 100 kept: all kept + smallest flat indices among exact -1.0 ties
        for (int i = tid; i < 8000; i += FBS) {
            float v = cs[i];
            if (v > -0.5f) {
                unsigned slot = atomicAdd(&sh_cnt, 1u);
                buf[slot] = (((unsigned long long)__float_as_uint(v)) << 32) | (unsigned)(~i);
            }
        }
        __syncthreads();
        if (tid == 0) {
            unsigned need = TOPK - Kp, got = 0;
            for (int i = 0; i < 8000 && got < need; ++i)
                if (cs[i] <= -0.5f) { buf[Kp + got] = (unsigned)(~i); got++; }
        }
    }
    __syncthreads();

    // rank-by-count epilogue (keys unique via distinct ~i)
    const int M2 = (Kp >= TOPK) ? (int)min(sh_cnt, 512u) : (int)TOPK;
    for (int i = tid; i < M2; i += FBS) {
        unsigned long long key = buf[i];
        int rank = 0;
        for (int j = 0; j < M2; ++j) rank += (buf[j] > key);
        if (rank < TOPK) {
            int fi = (int)(~(unsigned)key);
            int c = fi / TOPK; int kk = fi - c * TOPK;
            float4 bb = top_b[((size_t)b * NCLS + c) * TOPK + kk];
            int base = (b * TOPK + rank) * 6;
            out[base + 0] = bb.x; out[base + 1] = bb.y;
            out[base + 2] = bb.z; out[base + 3] = bb.w;
            out[base + 4] = cs[fi]; out[base + 5] = (float)c;
        }
    }
}

// ---------------------------------------------------------------------------
extern "C" void kernel_launch(void* const* d_in, const int* in_sizes, int n_in,
                              void* d_out, int out_size, void* d_ws, size_t ws_size,
                              hipStream_t stream) {
    (void)n_in; (void)out_size; (void)ws_size;
    const float* f0      = (const float*)d_in[0];
    const float* f1      = (const float*)d_in[1];
    const float* f2      = (const float*)d_in[2];
    const float* anchors = (const float*)d_in[3];
    const float* imshape = (const float*)d_in[4];
    const int B = in_sizes[0] / (255 * 19 * 19);

    char* ws = (char*)d_ws;
    size_t o = 0;
    float*  conf_q = (float*)(ws + o);  o += (size_t)B * KPAD * sizeof(float);
    float4* top_b  = (float4*)(ws + o); o += (size_t)B * NCLS * TOPK * sizeof(float4);
    float*  cand   = (float*)(ws + o);  o += (size_t)B * NCLS * TOPK * sizeof(float);
    float*  out    = (float*)d_out;

    const int total = B * NTOT;
    k_conf<<<(total + 255) / 256, 256, 0, stream>>>(f0, f1, f2, conf_q, total);
    k_topk<<<B * NCLS, NT, 0, stream>>>(f0, f1, f2, conf_q, anchors, imshape,
                                        top_b, cand);
    k_final<<<B, FBS, 0, stream>>>(cand, top_b, out);
}

// Round 16
// 238.721 us; speedup vs baseline: 1.1241x; 1.1241x over previous
//
#include <hip/hip_runtime.h>

// ---------------------------------------------------------------------------
// YOLOv3 post-processing pipeline (round 22 = round 18, the best-measured
// configuration at 239.2us; restored after r19/r20/r21 experiments all
// regressed or were neutral).
//   K1 k_conf : conf-only producer (1 coalesced load + sigmoid + 1 coalesced
//               store per anchor).
//   K2 k_topk : 512 thr, (512,4). Keygen with FUSED histogram (r15 win);
//               sequential vector loads (6 ILP/structural restructures all
//               regressed: r10/r12/r13/r14/r16/r17/r19/r21); register-
//               resident collect with exact rescore; rank-by-count; inline
//               winner box decode; fused greedy NMS.
//   K3 k_final: per-image top-100 of 8000, 1024 threads.
// ---------------------------------------------------------------------------

#define NTOT   22743      // 3*(19^2 + 38^2 + 76^2)
#define NCLS   80
#define TOPK   100
#define KPAD   22752      // row stride for conf_q (16B aligned, 8-div)
#define NG2    2166       // 8-key groups in layer 2 (17328 keys)
#define Q_L1   17328
#define Q_L0   21660
#define SCORE_THR 0.2f
#define NMS_THR   0.3f

__device__ __forceinline__ float sig_exact(float x) {
    return 1.0f / (1.0f + expf(-x));          // precise OCML expf + IEEE div
}
__device__ __forceinline__ float sig_fast(float x) {
    // monotone surrogate, rel err ~1e-6 << 2^-7 bin margin
    return __builtin_amdgcn_rcpf(1.0f + __expf(-x));
}
__device__ __forceinline__ unsigned pack2(float cfa, float lga, float cfb, float lgb) {
    unsigned ka = __float_as_uint(cfa * sig_fast(lga)) >> 16;
    unsigned kb = __float_as_uint(cfb * sig_fast(lgb)) >> 16;
    return ka | (kb << 16);
}

// -------------------------- K1: conf-only producer ------------------------
__global__ __launch_bounds__(256) void k_conf(
    const float* __restrict__ f0, const float* __restrict__ f1,
    const float* __restrict__ f2, float* __restrict__ conf_q, int total) {
    int gid = blockIdx.x * 256 + threadIdx.x;
    if (gid >= total) return;
    int b = gid / NTOT; int q = gid - b * NTOT;
    const float* f; int ghw, a, s;
    if (q < Q_L1)      { f = f2; ghw = 5776; a = q / 5776;  s = q - a * 5776; }
    else if (q < Q_L0) { f = f1; ghw = 1444; int r = q - Q_L1; a = r / 1444; s = r - a * 1444; }
    else               { f = f0; ghw = 361;  int r = q - Q_L0; a = r / 361;  s = r - a * 361; }
    // consecutive q -> consecutive s within a plane: coalesced load & store
    float tc = f[((size_t)(b * 255 + a * 85 + 4)) * ghw + s];
    conf_q[(size_t)b * KPAD + q] = sig_exact(tc);
}

// ------------------ shared select helpers ---------------------------------
__device__ void find_pivot(unsigned* hist, int H, unsigned target,
                           unsigned* suf, unsigned* sh_p, unsigned* sh_above) {
    const int tid = threadIdx.x;
    const int per = H >> 8;
    if (tid < 256) {
        unsigned acc = 0;
        for (int u = 0; u < per; ++u) acc += hist[tid * per + u];
        suf[tid] = acc;
    }
    __syncthreads();
    for (int off = 1; off < 256; off <<= 1) {
        unsigned v = 0;
        if (tid < 256) v = (tid + off < 256) ? suf[tid + off] : 0u;
        __syncthreads();
        if (tid < 256) suf[tid] += v;
        __syncthreads();
    }
    if (tid < 256) {
        unsigned mysuf = suf[tid];
        unsigned nxt = (tid == 255) ? 0u : suf[tid + 1];
        if (mysuf >= target && nxt < target) {
            unsigned above = nxt;
            for (int h = tid * per + per - 1; h >= tid * per; --h) {
                unsigned c2 = above + hist[h];
                if (c2 >= target) { *sh_p = (unsigned)h; *sh_above = above; break; }
                above = c2;
            }
        }
    }
    __syncthreads();
}

// -------------------------- K2: fused topk + NMS --------------------------
__device__ __forceinline__ void collect_cand(
    int b, int c, int q, const float* __restrict__ f0,
    const float* __restrict__ f1, const float* __restrict__ f2,
    const float* __restrict__ conf_q, unsigned long long* buf,
    unsigned* sh_cnt) {
    int a, s, nbase, ghw;
    const float* f;
    if (q < Q_L1)      { a = q / 5776;  s = q - a * 5776;  f = f2; ghw = 5776; nbase = 5415; }
    else if (q < Q_L0) { int r = q - Q_L1; a = r / 1444; s = r - a * 1444; f = f1; ghw = 1444; nbase = 1083; }
    else               { int r = q - Q_L0; a = r / 361;  s = r - a * 361;  f = f0; ghw = 361;  nbase = 0;    }
    float t  = f[((size_t)(b * 255 + a * 85 + 5 + c)) * ghw + s];
    float cf = conf_q[(size_t)b * KPAD + q];
    float sce = cf * sig_exact(t);
    int n = nbase + 3 * s + a;
    unsigned slot = atomicAdd(sh_cnt, 1u);
    if (slot < 512)
        buf[slot] = (((unsigned long long)__float_as_uint(sce)) << 32)
                    | (unsigned)(~n);
}

__device__ __forceinline__ void hist8(unsigned* histp, unsigned w0, unsigned w1,
                                      unsigned w2, unsigned w3) {
    unsigned ks[8] = { w0 & 0xFFFFu, w0 >> 16, w1 & 0xFFFFu, w1 >> 16,
                       w2 & 0xFFFFu, w2 >> 16, w3 & 0xFFFFu, w3 >> 16 };
    #pragma unroll
    for (int j = 0; j < 8; ++j)
        atomicAdd(&histp[ks[j] >> 2], 1u << (((ks[j] >> 1) & 1u) * 16));
}

__global__ __launch_bounds__(512, 4) void k_topk(
    const float* __restrict__ f0, const float* __restrict__ f1,
    const float* __restrict__ f2, const float* __restrict__ conf_q,
    const float* __restrict__ anchors, const float* __restrict__ imshape,
    float4* __restrict__ top_b, float* __restrict__ cand) {
    __shared__ unsigned int histp[4096];           // packed u16x2: 8192 bins, 16 KB
    __shared__ unsigned long long buf[512];        // 4 KB
    __shared__ unsigned int wsum[4];
    __shared__ float sb_y1[TOPK], sb_x1[TOPK], sb_y2[TOPK], sb_x2[TOPK], sb_s[TOPK];
    __shared__ unsigned int sh_p, sh_cnt;

    const int tid = threadIdx.x;
    const int row = blockIdx.x;
    const int b = row / NCLS, c = row - b * NCLS;
    const float* cq = conf_q + (size_t)b * KPAD;

    for (int i = tid; i < 4096; i += 512) histp[i] = 0;
    if (tid == 0) sh_cnt = 0;
    __syncthreads();                               // hist zeroed BEFORE keygen

    // ---- keygen + histogram FUSED (r15 form -- proven local optimum) -----
    // layer 2: 5 groups/thread
    uint4 v[5];
    bool  val[5];
    #pragma unroll
    for (int k = 0; k < 5; ++k) {
        int g = tid + k * 512;
        val[k] = (g < NG2);
        if (val[k]) {
            int q = g * 8;
            int a = q / 5776, s = q - a * 5776;
            const float* fp = f2 + ((size_t)(b * 255 + a * 85 + 5 + c)) * 5776 + s;
            float4 l0 = *(const float4*)fp;
            float4 l1 = *(const float4*)(fp + 4);
            float4 c0 = *(const float4*)(cq + q);
            float4 c1 = *(const float4*)(cq + q + 4);
            v[k].x = pack2(c0.x, l0.x, c0.y, l0.y);
            v[k].y = pack2(c0.z, l0.z, c0.w, l0.w);
            v[k].z = pack2(c1.x, l1.x, c1.y, l1.y);
            v[k].w = pack2(c1.z, l1.z, c1.w, l1.w);
            hist8(histp, v[k].x, v[k].y, v[k].z, v[k].w);
        } else v[k] = make_uint4(0, 0, 0, 0);
    }

    // layer 1: 3 whole planes, one float4/thread (tid<361), fused atomics
    const bool lv = (tid < 361);
    unsigned k1p[6];
    if (lv) {
        #pragma unroll
        for (int p = 0; p < 3; ++p) {
            const float* fp = f1 + ((size_t)(b * 255 + p * 85 + 5 + c)) * 1444 + 4 * tid;
            float4 lg = *(const float4*)fp;
            float4 cf = *(const float4*)(cq + Q_L1 + p * 1444 + 4 * tid);
            unsigned w0 = pack2(cf.x, lg.x, cf.y, lg.y);
            unsigned w1 = pack2(cf.z, lg.z, cf.w, lg.w);
            k1p[2*p] = w0; k1p[2*p+1] = w1;
            unsigned ks[4] = { w0 & 0xFFFFu, w0 >> 16, w1 & 0xFFFFu, w1 >> 16 };
            #pragma unroll
            for (int j = 0; j < 4; ++j)
                atomicAdd(&histp[ks[j] >> 2], 1u << (((ks[j] >> 1) & 1u) * 16));
        }
    }

    // layer 0: 3 planes, one scalar/thread (tid<361), fused atomics
    unsigned k0[3];
    if (lv) {
        #pragma unroll
        for (int p = 0; p < 3; ++p) {
            float g0 = f0[((size_t)(b * 255 + p * 85 + 5 + c)) * 361 + tid];
            float c0 = cq[Q_L0 + p * 361 + tid];
            k0[p] = __float_as_uint(c0 * sig_fast(g0)) >> 16;
            atomicAdd(&histp[k0[p] >> 2], 1u << (((k0[p] >> 1) & 1u) * 16));
        }
    }
    __syncthreads();

    // pivot: group t (tid<256) covers bins [t*32,t*32+32) = words [t*16,t*16+16)
    {
        const int lane = tid & 63;
        unsigned own = 0;
        if (tid < 256) {
            #pragma unroll
            for (int u = 0; u < 16; ++u) {
                unsigned w = histp[tid * 16 + u];
                own += (w & 0xFFFFu) + (w >> 16);
            }
        }
        unsigned acc = own;                        // wave-level suffix scan
        #pragma unroll
        for (int d = 1; d < 64; d <<= 1) {
            unsigned vv = __shfl_down(acc, d, 64);
            if (lane + d < 64) acc += vv;
        }
        if (tid < 256 && lane == 0) wsum[tid >> 6] = acc;
        __syncthreads();
        if (tid < 256) {
            unsigned tail = 0;
            for (int w2 = (tid >> 6) + 1; w2 < 4; ++w2) tail += wsum[w2];
            unsigned suft = acc + tail;            // suffix incl own group
            unsigned nxt  = suft - own;            // suffix of groups above
            if (suft >= TOPK && nxt < TOPK) {
                unsigned above = nxt;
                for (int bb = 31; bb >= 0; --bb) {
                    unsigned w = histp[tid * 16 + (bb >> 1)];
                    unsigned cnt = (bb & 1) ? (w >> 16) : (w & 0xFFFFu);
                    if (above + cnt >= TOPK) { sh_p = (unsigned)(tid * 32 + bb); break; }
                    above += cnt;
                }
            }
        }
        __syncthreads();
    }
    const unsigned kthr = sh_p > 0 ? ((sh_p - 1) << 1) : 0u;  // one-bin margin

    // pass 2: collect candidates FROM REGISTERS, exact rescore
    #pragma unroll
    for (int k = 0; k < 5; ++k) if (val[k]) {
        unsigned ks[8] = { v[k].x & 0xFFFFu, v[k].x >> 16, v[k].y & 0xFFFFu, v[k].y >> 16,
                           v[k].z & 0xFFFFu, v[k].z >> 16, v[k].w & 0xFFFFu, v[k].w >> 16 };
        #pragma unroll
        for (int j = 0; j < 8; ++j)
            if (ks[j] >= kthr)
                collect_cand(b, c, (tid + k * 512) * 8 + j, f0, f1, f2, conf_q, buf, &sh_cnt);
    }
    if (lv) {
        #pragma unroll
        for (int p = 0; p < 3; ++p) {
            unsigned ks[4] = { k1p[2*p] & 0xFFFFu, k1p[2*p] >> 16,
                               k1p[2*p+1] & 0xFFFFu, k1p[2*p+1] >> 16 };
            #pragma unroll
            for (int j = 0; j < 4; ++j)
                if (ks[j] >= kthr)
                    collect_cand(b, c, Q_L1 + p * 1444 + 4 * tid + j, f0, f1, f2, conf_q, buf, &sh_cnt);
            if (k0[p] >= kthr)
                collect_cand(b, c, Q_L0 + p * 361 + tid, f0, f1, f2, conf_q, buf, &sh_cnt);
        }
    }
    __syncthreads();

    // rank-by-count; box decoded INLINE for rank<TOPK only (r18-verified)
    const int M = (int)min(sh_cnt, 512u);
    if (tid < M) {
        unsigned long long mykey = buf[tid];
        int rank = 0;
        for (int j = 0; j < M; ++j) rank += (buf[j] > mykey);   // LDS broadcast
        if (rank < TOPK) {
            int nn = (int)(~(unsigned)mykey);
            const float* f; int ghw, gw, l, off;
            if (nn < 1083)      { f = f0; off = 0;    ghw = 361;  gw = 19; l = 0; }
            else if (nn < 5415) { f = f1; off = 1083; ghw = 1444; gw = 38; l = 1; }
            else                { f = f2; off = 5415; ghw = 5776; gw = 76; l = 2; }
            int m2 = nn - off; int a = m2 % 3; int s = m2 / 3;
            int y = s / gw, x = s - y * gw;
            const float* qp = f + ((size_t)(b * 255 + a * 85)) * ghw + s;
            float tx = qp[0], ty = qp[(size_t)ghw];
            float tw = qp[2 * (size_t)ghw], th = qp[3 * (size_t)ghw];
            int arow = (2 - l) * 3 + a;
            float aw = anchors[arow * 2], ah = anchors[arow * 2 + 1];
            float imh = imshape[0], imw = imshape[1];
            float gf = (float)gw;
            float bxx = (sig_exact(tx) + (float)x) / gf;
            float bxy = (sig_exact(ty) + (float)y) / gf;
            float bw  = expf(tw) * aw / 608.0f;
            float bh  = expf(th) * ah / 608.0f;
            float r  = fminf(608.0f / imh, 608.0f / imw);
            float nh = rintf(imh * r), nw2 = rintf(imw * r);
            float offy = (608.0f - nh) / 2.0f / 608.0f;
            float offx = (608.0f - nw2) / 2.0f / 608.0f;
            float scy = 608.0f / nh, scx = 608.0f / nw2;
            float cy = (bxy - offy) * scy;
            float cx = (bxx - offx) * scx;
            float hh = bh * scy, ww = bw * scx;
            float4 bx = make_float4((cy - hh / 2.0f) * imh, (cx - ww / 2.0f) * imw,
                                    (cy + hh / 2.0f) * imh, (cx + ww / 2.0f) * imw);
            sb_y1[rank] = bx.x; sb_x1[rank] = bx.y;
            sb_y2[rank] = bx.z; sb_x2[rank] = bx.w;
            sb_s[rank]  = __uint_as_float((unsigned)(mykey >> 32));
            top_b[(size_t)row * TOPK + rank] = bx;
        }
    }
    __syncthreads();

    // fused greedy NMS on wave 0 (reference-exact op order)
    if (tid < 64) {
        const int j0 = tid, j1 = tid + 64;
        const bool v1 = (j1 < TOPK);
        float y10 = sb_y1[j0], x10 = sb_x1[j0], y20 = sb_y2[j0], x20 = sb_x2[j0];
        float s0 = sb_s[j0];
        float y11 = v1 ? sb_y1[j1] : 0.f, x11 = v1 ? sb_x1[j1] : 0.f;
        float y21 = v1 ? sb_y2[j1] : 0.f, x21 = v1 ? sb_x2[j1] : 0.f;
        float s1 = v1 ? sb_s[j1] : -1.0f;
        float ar0 = fmaxf(y20 - y10, 0.f) * fmaxf(x20 - x10, 0.f);
        float ar1 = fmaxf(y21 - y11, 0.f) * fmaxf(x21 - x11, 0.f);
        int sup0 = 0, sup1 = 0;
        for (int i = 0; i < TOPK; ++i) {
            float yi1 = sb_y1[i], xi1 = sb_x1[i], yi2 = sb_y2[i], xi2 = sb_x2[i];
            float si = sb_s[i];
            int supi = (i < 64) ? __shfl(sup0, i, 64) : __shfl(sup1, i - 64, 64);
            bool keep_i = (si >= SCORE_THR) && (supi == 0);
            if (keep_i) {
                float ari = fmaxf(yi2 - yi1, 0.f) * fmaxf(xi2 - xi1, 0.f);
                if (j0 > i) {
                    float ty1 = fmaxf(yi1, y10), tx1 = fmaxf(xi1, x10);
                    float ty2 = fminf(yi2, y20), tx2 = fminf(xi2, x20);
                    float inter = fmaxf(ty2 - ty1, 0.f) * fmaxf(tx2 - tx1, 0.f);
                    float iou = inter / (ari + ar0 - inter + 1e-9f);
                    if (iou > NMS_THR) sup0 = 1;
                }
                if (v1 && j1 > i) {
                    float ty1 = fmaxf(yi1, y11), tx1 = fmaxf(xi1, x11);
                    float ty2 = fminf(yi2, y21), tx2 = fminf(xi2, x21);
                    float inter = fmaxf(ty2 - ty1, 0.f) * fmaxf(tx2 - tx1, 0.f);
                    float iou = inter / (ari + ar1 - inter + 1e-9f);
                    if (iou > NMS_THR) sup1 = 1;
                }
            }
        }
        cand[(size_t)row * TOPK + j0] = (s0 >= SCORE_THR && sup0 == 0) ? s0 : -1.0f;
        if (v1)
            cand[(size_t)row * TOPK + j1] = (s1 >= SCORE_THR && sup1 == 0) ? s1 : -1.0f;
    }
}

// -------------------------- K3: per-image top-100 -------------------------
#define FBS 1024
__global__ __launch_bounds__(FBS) void k_final(
    const float* __restrict__ cand, const float4* __restrict__ top_b,
    float* __restrict__ out) {
    __shared__ float cs[8000];                     // 32 KB
    __shared__ unsigned int hist[4096];            // 16 KB
    __shared__ unsigned long long buf[512];
    __shared__ unsigned int suf[256];
    __shared__ unsigned int sh_kp, sh_p1, sh_above1, sh_p2, sh_above2, sh_cnt;

    const int tid = threadIdx.x, b = blockIdx.x;
    if (tid == 0) { sh_kp = 0; sh_cnt = 0; }
    for (int i = tid; i < 4096; i += FBS) hist[i] = 0;
    __syncthreads();

    unsigned lk = 0;
    for (int i = tid; i < 8000; i += FBS) {
        float v = cand[b * 8000 + i];
        cs[i] = v;
        if (v > -0.5f) lk++;
    }
    atomicAdd(&sh_kp, lk);
    __syncthreads();
    unsigned Kp = sh_kp;

    if (Kp >= TOPK) {
        for (int i = tid; i < 8000; i += FBS)
            if (cs[i] > -0.5f) atomicAdd(&hist[__float_as_uint(cs[i]) >> 19], 1u);
        __syncthreads();
        find_pivot(hist, 2048, TOPK, suf, &sh_p1, &sh_above1);
        unsigned p1 = sh_p1, above1 = sh_above1;
        for (int i = tid; i < 4096; i += FBS) hist[i] = 0;
        __syncthreads();
        for (int i = tid; i < 8000; i += FBS) {
            float v = cs[i];
            if (v > -0.5f) {
                unsigned bits = __float_as_uint(v);
                if ((bits >> 19) == p1) atomicAdd(&hist[(bits >> 7) & 0xFFFu], 1u);
            }
        }
        __syncthreads();
        find_pivot(hist, 4096, TOPK - above1, suf, &sh_p2, &sh_above2);
        unsigned p2 = sh_p2;
        for (int i = tid; i < 8000; i += FBS) {
            float v = cs[i];
            if (v > -0.5f) {
                unsigned bits = __float_as_uint(v);
                unsigned b1 = bits >> 19;
                if (b1 > p1 || (b1 == p1 && ((bits >> 7) & 0xFFFu) >= p2)) {
                    unsigned slot = atomicAdd(&sh_cnt, 1u);
                    if (slot < 512)
                        buf[slot] = (((unsigned long long)bits) << 32) | (unsigned)(~i);
                }
            }
        }
    } else {
        // < 100 kept: all kept + smallest flat indices among exact -1.0 ties
        for (int i = tid; i < 8000; i += FBS) {
            float v = cs[i];
            if (v > -0.5f) {
                unsigned slot = atomicAdd(&sh_cnt, 1u);
                buf[slot] = (((unsigned long long)__float_as_uint(v)) << 32) | (unsigned)(~i);
            }
        }
        __syncthreads();
        if (tid == 0) {
            unsigned need = TOPK - Kp, got = 0;
            for (int i = 0; i < 8000 && got < need; ++i)
                if (cs[i] <= -0.5f) { buf[Kp + got] = (unsigned)(~i); got++; }
        }
    }
    __syncthreads();

    // rank-by-count epilogue (keys unique via distinct ~i)
    const int M2 = (Kp >= TOPK) ? (int)min(sh_cnt, 512u) : (int)TOPK;
    for (int i = tid; i < M2; i += FBS) {
        unsigned long long key = buf[i];
        int rank = 0;
        for (int j = 0; j < M2; ++j) rank += (buf[j] > key);
        if (rank < TOPK) {
            int fi = (int)(~(unsigned)key);
            int c = fi / TOPK; int kk = fi - c * TOPK;
            float4 bb = top_b[((size_t)b * NCLS + c) * TOPK + kk];
            int base = (b * TOPK + rank) * 6;
            out[base + 0] = bb.x; out[base + 1] = bb.y;
            out[base + 2] = bb.z; out[base + 3] = bb.w;
            out[base + 4] = cs[fi]; out[base + 5] = (float)c;
        }
    }
}

// ---------------------------------------------------------------------------
extern "C" void kernel_launch(void* const* d_in, const int* in_sizes, int n_in,
                              void* d_out, int out_size, void* d_ws, size_t ws_size,
                              hipStream_t stream) {
    (void)n_in; (void)out_size; (void)ws_size;
    const float* f0      = (const float*)d_in[0];
    const float* f1      = (const float*)d_in[1];
    const float* f2      = (const float*)d_in[2];
    const float* anchors = (const float*)d_in[3];
    const float* imshape = (const float*)d_in[4];
    const int B = in_sizes[0] / (255 * 19 * 19);

    char* ws = (char*)d_ws;
    size_t o = 0;
    float*  conf_q = (float*)(ws + o);  o += (size_t)B * KPAD * sizeof(float);
    float4* top_b  = (float4*)(ws + o); o += (size_t)B * NCLS * TOPK * sizeof(float4);
    float*  cand   = (float*)(ws + o);  o += (size_t)B * NCLS * TOPK * sizeof(float);
    float*  out    = (float*)d_out;

    const int total = B * NTOT;
    k_conf<<<(total + 255) / 256, 256, 0, stream>>>(f0, f1, f2, conf_q, total);
    k_topk<<<B * NCLS, 512, 0, stream>>>(f0, f1, f2, conf_q, anchors, imshape,
                                         top_b, cand);
    k_final<<<B, FBS, 0, stream>>>(cand, top_b, out);
}